// Round 7
// baseline (1722.599 us; speedup 1.0000x reference)
//
#include <hip/hip_runtime.h>

#define NTHREADS 512

typedef __attribute__((ext_vector_type(8))) short s16x8;
typedef __attribute__((ext_vector_type(4))) float f32x4;
typedef __attribute__((ext_vector_type(4))) unsigned int u32x4;

__device__ __forceinline__ unsigned short f2bf(float f) {
  unsigned u = __float_as_uint(f);
  u += 0x7fffu + ((u >> 16) & 1u);
  return (unsigned short)(u >> 16);
}
__device__ __forceinline__ float bf2f(unsigned short s) {
  return __uint_as_float(((unsigned)s) << 16);
}
__device__ __forceinline__ float sigm(float x) {
  return __builtin_amdgcn_rcpf(1.0f + __expf(-x));
}
__device__ __forceinline__ float tanh_fast(float x) {
  return 1.0f - 2.0f * __builtin_amdgcn_rcpf(1.0f + __expf(2.0f * x));
}

// MFMA with C/D pinned to AGPRs. Register-file discipline (rounds 1-6):
// the RA splits the unified file ~128 arch + 128 acc at this occupancy.
// Round 6 had AGPR demand exactly 128 (acc 64 + c 64) -> zero slack ->
// copies/spills persisted. This round c-state moves to HBM ws, leaving
// AGPR = acc 64 only (50% slack) and arch ~100 <= 128.
__device__ __forceinline__ void mfma_bf16_acc(u32x4 a, u32x4 b, f32x4& c) {
  union { u32x4 u; s16x8 s; } ua, ub;
  ua.u = a; ub.u = b;
  asm("v_mfma_f32_16x16x32_bf16 %0, %1, %2, %0"
      : "+a"(c)
      : "v"(ua.s), "v"(ub.s));
}

// ---------------- weight pre-pack (unchanged, verified) ----------------
// W0p: layer0 combined [n=4H][K=416] (k<160: W_ih0, else W_hh0), bf16,
//      layout [nblk][kblk][16 n][8 k]; W1p: layer1 K=512, KB=64.
// b0/b1: b_ih + b_hh pre-summed, f32.
__global__ void pack_weights(const float* __restrict__ Wih0, const float* __restrict__ Whh0,
                             const float* __restrict__ bih0, const float* __restrict__ bhh0,
                             const float* __restrict__ Wih1, const float* __restrict__ Whh1,
                             const float* __restrict__ bih1, const float* __restrict__ bhh1,
                             unsigned short* __restrict__ W0p, unsigned short* __restrict__ W1p,
                             float* __restrict__ b0, float* __restrict__ b1) {
  int e = blockIdx.x * 256 + threadIdx.x;
  const int N0 = 1024 * 416;
  const int N1 = 1024 * 512;
  if (e < N0) {
    int kk = e & 7, t1 = e >> 3;
    int n = t1 & 15, t2 = t1 >> 4;
    int kb = t2 % 52, nb = t2 / 52;
    int gn = nb * 16 + n, k = kb * 8 + kk;
    float v = (k < 160) ? Wih0[gn * 160 + k] : Whh0[gn * 256 + (k - 160)];
    W0p[e] = f2bf(v);
  } else if (e < N0 + N1) {
    int e2 = e - N0;
    int kk = e2 & 7, t1 = e2 >> 3;
    int n = t1 & 15, t2 = t1 >> 4;
    int kb = t2 & 63, nb = t2 >> 6;
    int gn = nb * 16 + n, k = kb * 8 + kk;
    float v = (k < 256) ? Wih1[gn * 256 + k] : Whh1[gn * 256 + (k - 256)];
    W1p[e2] = f2bf(v);
  } else if (e < N0 + N1 + 1024) {
    int n = e - (N0 + N1);
    b0[n] = bih0[n] + bhh0[n];
  } else if (e < N0 + N1 + 2048) {
    int n = e - (N0 + N1 + 1024);
    b1[n] = bih1[n] + bhh1[n];
  }
}

// ---------------- fused 2-layer LSTM + FC ----------------
// 256 blocks x 512 threads; block owns 64 batch rows for all 10 steps.
// LDS 158 KB (1 blk/CU, 2 waves/SIMD): x-tile + DOUBLE-BUFFERED h1/h2 in
// bf16 A-layout [kblk][row][8k] + biases; 3 barriers/step.
// c-state lives in HBM ws (coalesced f32x4 per (layer,jt,rt) slot), read+
// written once per layer per step; t==0 reads are skipped (ws is poisoned).
// Register plan: AGPR = acc 64 only; arch = av dbuf 32 + bv dbuf 32 +
// temps ~35 <= 128 hard cap.
__global__ __attribute__((amdgpu_flat_work_group_size(NTHREADS, NTHREADS),
                          amdgpu_waves_per_eu(2, 2)))
void lstm_fused(const float* __restrict__ x,
                const unsigned short* __restrict__ W0p,
                const unsigned short* __restrict__ W1p,
                const float* __restrict__ b0,
                const float* __restrict__ b1,
                const float* __restrict__ Wfc,
                const float* __restrict__ bfc,
                float* __restrict__ cws,
                float* __restrict__ out) {
  __shared__ unsigned int lds_x[20 * 64 * 4];   // 20480 B
  __shared__ unsigned int lds_h1[16384];        // 65536 B = 2 bufs x [32 kblk][64 row][8k]
  __shared__ unsigned int lds_h2[16384];        // 65536 B
  __shared__ float lds_red[512];                // 2048 B
  __shared__ float lds_b0[1024];                // 4096 B
  __shared__ float lds_b1[1024];                // 4096 B   total 161792 B

  const int tid = threadIdx.x;
  const int wave = tid >> 6;
  const int lane = tid & 63;
  const int l15 = lane & 15;
  const int quad = lane >> 4;
  const long rowg0 = (long)blockIdx.x * 64;

  for (int i = tid; i < 16384; i += NTHREADS) { lds_h1[i] = 0u; lds_h2[i] = 0u; }
  for (int i = tid; i < 1024; i += NTHREADS) { lds_b0[i] = b0[i]; lds_b1[i] = b1[i]; }

  float fc_acc = 0.0f;

  const u32x4* lxs = (const u32x4*)lds_x;
  const u32x4* lh1 = (const u32x4*)lds_h1;
  const u32x4* lh2 = (const u32x4*)lds_h2;
  unsigned short* lh1s = (unsigned short*)lds_h1;
  unsigned short* lh2s = (unsigned short*)lds_h2;
  const u32x4* w0q = (const u32x4*)W0p;
  const u32x4* w1q = (const u32x4*)W1p;

  // c-state ws base for this block: [blk][layer(2)][jt(2)][rt(4)][tid(512)*4]
  float* cblk = cws + (long)blockIdx.x * (2 * 2 * 4 * NTHREADS * 4) + (tid << 2);

  for (int t = 0; t < 10; t++) {
    const int rd = t & 1;        // prev-h buffer
    const int wr = rd ^ 1;       // new-h buffer

    // ---- stage x_t -> lds_x (bf16 A-layout) ----
#pragma unroll
    for (int s = 0; s < 5; s++) {
      int p = tid + s * NTHREADS;          // 2560 f32x4 = 64 rows x 40 quads
      int row = p / 40;
      int kq = p - row * 40;
      const f32x4 v = __builtin_nontemporal_load(
          (const f32x4*)(x + (rowg0 + row) * 1600 + t * 160 + kq * 4));
      unsigned lo = (unsigned)f2bf(v[0]) | ((unsigned)f2bf(v[1]) << 16);
      unsigned hi = (unsigned)f2bf(v[2]) | ((unsigned)f2bf(v[3]) << 16);
      int base = (kq >> 1) * 256 + row * 4 + (kq & 1) * 2;
      lds_x[base] = lo;
      lds_x[base + 1] = hi;
    }
    __syncthreads();  // B1: x staged; h1[rd] stable from prev step

    // ======== layer 0: K=416 ([x_t | h1_prev]) ========
#pragma unroll
    for (int jt = 0; jt < 2; jt++) {
      const int nbb = wave * 2 + jt;
      f32x4 acc[4][4];
#pragma unroll
      for (int g = 0; g < 4; g++)
#pragma unroll
        for (int rt = 0; rt < 4; rt++) acc[g][rt] = (f32x4){0.f, 0.f, 0.f, 0.f};

      u32x4 av[2][4], bv[2][4];
#pragma unroll
      for (int g = 0; g < 4; g++)
        bv[0][g] = w0q[((g * 16 + nbb) * 52 + quad) * 16 + l15];
#pragma unroll
      for (int rt = 0; rt < 4; rt++) av[0][rt] = lxs[quad * 64 + rt * 16 + l15];

#pragma unroll
      for (int ki = 0; ki < 13; ki++) {
        const int cur = ki & 1, nxt = cur ^ 1;
        if (ki < 12) {
          const int k0n = (ki + 1) * 32;
#pragma unroll
          for (int g = 0; g < 4; g++)
            bv[nxt][g] = w0q[((g * 16 + nbb) * 52 + (ki + 1) * 4 + quad) * 16 + l15];
          const u32x4* ab = (k0n < 160)
              ? (lxs + ((k0n >> 3) + quad) * 64)
              : (lh1 + rd * 2048 + (((k0n - 160) >> 3) + quad) * 64);
#pragma unroll
          for (int rt = 0; rt < 4; rt++) av[nxt][rt] = ab[rt * 16 + l15];
        }
#pragma unroll
        for (int g = 0; g < 4; g++)
#pragma unroll
          for (int rt = 0; rt < 4; rt++)
            mfma_bf16_acc(av[cur][rt], bv[cur][g], acc[g][rt]);
      }
      // epilogue: gates + c (HBM ws) -> new c, h1 -> lds_h1[wr]
      float b_i = lds_b0[0 * 256 + wave * 32 + jt * 16 + l15];
      float b_f = lds_b0[1 * 256 + wave * 32 + jt * 16 + l15];
      float b_g = lds_b0[2 * 256 + wave * 32 + jt * 16 + l15];
      float b_o = lds_b0[3 * 256 + wave * 32 + jt * 16 + l15];
      float* cb = cblk + (0 * 2 + jt) * 4 * NTHREADS * 4;  // layer0, this jt
#pragma unroll
      for (int rt = 0; rt < 4; rt++) {
        f32x4 cold;
        if (t > 0) cold = *(const f32x4*)(cb + rt * NTHREADS * 4);
        else cold = (f32x4){0.f, 0.f, 0.f, 0.f};
        f32x4 cnew;
#pragma unroll
        for (int r = 0; r < 4; r++) {
          float iv = sigm(acc[0][rt][r] + b_i);
          float fv = sigm(acc[1][rt][r] + b_f);
          float gv = tanh_fast(acc[2][rt][r] + b_g);
          float ov = sigm(acc[3][rt][r] + b_o);
          float cn = fv * cold[r] + iv * gv;
          cnew[r] = cn;
          int row = rt * 16 + quad * 4 + r;
          int col = wave * 32 + jt * 16 + l15;
          lh1s[wr * 16384 + ((col >> 3) * 64 + row) * 8 + (col & 7)] =
              f2bf(ov * tanh_fast(cn));
        }
        *(f32x4*)(cb + rt * NTHREADS * 4) = cnew;
      }
    }
    __syncthreads();  // B2: h1[wr] complete

    // ======== layer 1: K=512 ([h1_new | h2_prev]) ========
#pragma unroll
    for (int jt = 0; jt < 2; jt++) {
      const int nbb = wave * 2 + jt;
      f32x4 acc[4][4];
#pragma unroll
      for (int g = 0; g < 4; g++)
#pragma unroll
        for (int rt = 0; rt < 4; rt++) acc[g][rt] = (f32x4){0.f, 0.f, 0.f, 0.f};

      u32x4 av[2][4], bv[2][4];
#pragma unroll
      for (int g = 0; g < 4; g++)
        bv[0][g] = w1q[((g * 16 + nbb) * 64 + quad) * 16 + l15];
#pragma unroll
      for (int rt = 0; rt < 4; rt++)
        av[0][rt] = lh1[wr * 2048 + quad * 64 + rt * 16 + l15];

#pragma unroll
      for (int ki = 0; ki < 16; ki++) {
        const int cur = ki & 1, nxt = cur ^ 1;
        if (ki < 15) {
          const int k0n = (ki + 1) * 32;
#pragma unroll
          for (int g = 0; g < 4; g++)
            bv[nxt][g] = w1q[((g * 16 + nbb) * 64 + (ki + 1) * 4 + quad) * 16 + l15];
          const u32x4* ab = (k0n < 256)
              ? (lh1 + wr * 2048 + ((k0n >> 3) + quad) * 64)
              : (lh2 + rd * 2048 + (((k0n - 256) >> 3) + quad) * 64);
#pragma unroll
          for (int rt = 0; rt < 4; rt++) av[nxt][rt] = ab[rt * 16 + l15];
        }
#pragma unroll
        for (int g = 0; g < 4; g++)
#pragma unroll
          for (int rt = 0; rt < 4; rt++)
            mfma_bf16_acc(av[cur][rt], bv[cur][g], acc[g][rt]);
      }
      float b_i = lds_b1[0 * 256 + wave * 32 + jt * 16 + l15];
      float b_f = lds_b1[1 * 256 + wave * 32 + jt * 16 + l15];
      float b_g = lds_b1[2 * 256 + wave * 32 + jt * 16 + l15];
      float b_o = lds_b1[3 * 256 + wave * 32 + jt * 16 + l15];
      float* cb = cblk + (1 * 2 + jt) * 4 * NTHREADS * 4;  // layer1, this jt
#pragma unroll
      for (int rt = 0; rt < 4; rt++) {
        f32x4 cold;
        if (t > 0) cold = *(const f32x4*)(cb + rt * NTHREADS * 4);
        else cold = (f32x4){0.f, 0.f, 0.f, 0.f};
        f32x4 cnew;
#pragma unroll
        for (int r = 0; r < 4; r++) {
          float iv = sigm(acc[0][rt][r] + b_i);
          float fv = sigm(acc[1][rt][r] + b_f);
          float gv = tanh_fast(acc[2][rt][r] + b_g);
          float ov = sigm(acc[3][rt][r] + b_o);
          float cn = fv * cold[r] + iv * gv;
          cnew[r] = cn;
          int row = rt * 16 + quad * 4 + r;
          int col = wave * 32 + jt * 16 + l15;
          lh2s[wr * 16384 + ((col >> 3) * 64 + row) * 8 + (col & 7)] =
              f2bf(ov * tanh_fast(cn));
        }
        *(f32x4*)(cb + rt * NTHREADS * 4) = cnew;
      }
    }
    __syncthreads();  // B3: h2[wr] complete

    // ---- FC partial: logit += W_fc[t*256 + j] * h2_new[row][j] ----
    {
      int row = tid >> 3;
      int jq = (tid & 7) * 32;
      float s = 0.f;
#pragma unroll
      for (int kb = 0; kb < 4; kb++) {
        u32x4 hv = lh2[wr * 2048 + ((jq >> 3) + kb) * 64 + row];
        const f32x4 wA = *(const f32x4*)(Wfc + t * 256 + jq + kb * 8);
        const f32x4 wB = *(const f32x4*)(Wfc + t * 256 + jq + kb * 8 + 4);
#pragma unroll
        for (int e = 0; e < 2; e++) {
          unsigned u = hv[e];
          s += bf2f((unsigned short)(u & 0xffffu)) * wA[2 * e];
          s += bf2f((unsigned short)(u >> 16)) * wA[2 * e + 1];
        }
#pragma unroll
        for (int e = 0; e < 2; e++) {
          unsigned u = hv[2 + e];
          s += bf2f((unsigned short)(u & 0xffffu)) * wB[2 * e];
          s += bf2f((unsigned short)(u >> 16)) * wB[2 * e + 1];
        }
      }
      fc_acc += s;
    }
    // no barrier: next staging touches lds_x only (last read before B2);
    // dbuf guarantees no h region is rewritten while readable.
  }

  lds_red[tid] = fc_acc;  // [row(64)][slot(8)]
  __syncthreads();
  if (tid < 64) {
    float s = 0.f;
#pragma unroll
    for (int e = 0; e < 8; e++) s += lds_red[tid * 8 + e];
    out[rowg0 + tid] = sigm(s + bfc[0]);
  }
}

extern "C" void kernel_launch(void* const* d_in, const int* in_sizes, int n_in,
                              void* d_out, int out_size, void* d_ws, size_t ws_size,
                              hipStream_t stream) {
  const float* x    = (const float*)d_in[0];
  const float* Wih0 = (const float*)d_in[1];
  const float* Whh0 = (const float*)d_in[2];
  const float* bih0 = (const float*)d_in[3];
  const float* bhh0 = (const float*)d_in[4];
  const float* Wih1 = (const float*)d_in[5];
  const float* Whh1 = (const float*)d_in[6];
  const float* bih1 = (const float*)d_in[7];
  const float* bhh1 = (const float*)d_in[8];
  const float* Wfc  = (const float*)d_in[9];
  const float* bfc  = (const float*)d_in[10];
  float* out = (float*)d_out;

  unsigned short* W0p = (unsigned short*)d_ws;         // 1024*416 bf16
  unsigned short* W1p = W0p + 1024 * 416;              // 1024*512 bf16
  float* b0 = (float*)(W1p + 1024 * 512);              // 1024 f32
  float* b1 = b0 + 1024;                               // 1024 f32
  float* cws = b1 + 1024;                              // 256*2*2*4*512*4 f32 = 64 MiB

  const int total = 1024 * 416 + 1024 * 512 + 2048;
  pack_weights<<<(total + 255) / 256, 256, 0, stream>>>(
      Wih0, Whh0, bih0, bhh0, Wih1, Whh1, bih1, bhh1, W0p, W1p, b0, b1);
  lstm_fused<<<256, NTHREADS, 0, stream>>>(x, W0p, W1p, b0, b1, Wfc, bfc, cws, out);
}

// Round 8
// 581.894 us; speedup vs baseline: 2.9603x; 2.9603x over previous
//
#include <hip/hip_runtime.h>

#define NTHREADS 512

typedef __attribute__((ext_vector_type(8))) short s16x8;
typedef __attribute__((ext_vector_type(4))) float f32x4;
typedef __attribute__((ext_vector_type(4))) unsigned int u32x4;

__device__ __forceinline__ unsigned short f2bf(float f) {
  unsigned u = __float_as_uint(f);
  u += 0x7fffu + ((u >> 16) & 1u);
  return (unsigned short)(u >> 16);
}
__device__ __forceinline__ float bf2f(unsigned short s) {
  return __uint_as_float(((unsigned)s) << 16);
}
__device__ __forceinline__ float sigm(float x) {
  return __builtin_amdgcn_rcpf(1.0f + __expf(-x));
}
__device__ __forceinline__ float tanh_fast(float x) {
  return 1.0f - 2.0f * __builtin_amdgcn_rcpf(1.0f + __expf(2.0f * x));
}
__device__ __forceinline__ f32x4 mfma_bf16(u32x4 a, u32x4 b, f32x4 c) {
  union { u32x4 u; s16x8 s; } ua, ub;
  ua.u = a; ub.u = b;
  return __builtin_amdgcn_mfma_f32_16x16x32_bf16(ua.s, ub.s, c, 0, 0, 0);
}
// persistent c-state parked in the acc half of the unified file (round 5/6:
// removes arch-side pressure; c touched only in epilogues)
__device__ __forceinline__ float agpr_st(float v) {
  float r;
  asm("v_accvgpr_write_b32 %0, %1" : "=a"(r) : "v"(v));
  return r;
}
__device__ __forceinline__ float agpr_ld(float a) {
  float r;
  asm("v_accvgpr_read_b32 %0, %1" : "=v"(r) : "a"(a));
  return r;
}

// ---------------- weight pre-pack ----------------
// NEW layout (rolled-loop friendly): [nb(16)][kb][g(4)][16 n][8 k], bf16.
//   W0p: kb in [0,52)  (k = kb*8: k<160 from W_ih0, else W_hh0)
//   W1p: kb in [0,64)  (k<256 from W_ih1, else W_hh1)
// Per k-group a wave advances ONE pointer by 4096 B; the 4 gate fragments
// are imm offsets 0/256/512/768 B. b0/b1: b_ih+b_hh pre-summed, f32.
__global__ void pack_weights(const float* __restrict__ Wih0, const float* __restrict__ Whh0,
                             const float* __restrict__ bih0, const float* __restrict__ bhh0,
                             const float* __restrict__ Wih1, const float* __restrict__ Whh1,
                             const float* __restrict__ bih1, const float* __restrict__ bhh1,
                             unsigned short* __restrict__ W0p, unsigned short* __restrict__ W1p,
                             float* __restrict__ b0, float* __restrict__ b1) {
  int e = blockIdx.x * 256 + threadIdx.x;
  const int N0 = 16 * 52 * 4 * 128;   // 425984
  const int N1 = 16 * 64 * 4 * 128;   // 524288
  if (e < N0) {
    int kk = e & 7, t1 = e >> 3;
    int n = t1 & 15, t2 = t1 >> 4;
    int g = t2 & 3, t3 = t2 >> 2;
    int kb = t3 % 52, nb = t3 / 52;
    int gn = g * 256 + nb * 16 + n, k = kb * 8 + kk;
    float v = (k < 160) ? Wih0[gn * 160 + k] : Whh0[gn * 256 + (k - 160)];
    W0p[e] = f2bf(v);
  } else if (e < N0 + N1) {
    int e2 = e - N0;
    int kk = e2 & 7, t1 = e2 >> 3;
    int n = t1 & 15, t2 = t1 >> 4;
    int g = t2 & 3, t3 = t2 >> 2;
    int kb = t3 & 63, nb = t3 >> 6;
    int gn = g * 256 + nb * 16 + n, k = kb * 8 + kk;
    float v = (k < 256) ? Wih1[gn * 256 + k] : Whh1[gn * 256 + (k - 256)];
    W1p[e2] = f2bf(v);
  } else if (e < N0 + N1 + 1024) {
    int n = e - (N0 + N1);
    b0[n] = bih0[n] + bhh0[n];
  } else if (e < N0 + N1 + 2048) {
    int n = e - (N0 + N1 + 1024);
    b1[n] = bih1[n] + bhh1[n];
  }
}

// ---- rolled, software-pipelined K-loop (N k-groups of 32) ----
// A and B fragment loads have identical shape: p[0],p[16],p[32],p[48]
// (imm offsets 0/256/512/768 B), pointer stride 256 u32x4 = 4096 B/group.
// Static 2-slot double buffer; #pragma unroll 1 keeps the body small
// (rounds 1-7: fully-unrolled K-loops -> ~20 KB/t-iter bodies, RA spills
// immune to budget, all pipes <10% busy at flat ~1500 us).
__device__ __forceinline__ void ld4(u32x4 d[4], const u32x4* p) {
  d[0] = p[0]; d[1] = p[16]; d[2] = p[32]; d[3] = p[48];
}
__device__ __forceinline__ void mfma16(const u32x4 a[4], const u32x4 b[4],
                                       f32x4 acc[4][4]) {
#pragma unroll
  for (int g = 0; g < 4; g++)
#pragma unroll
    for (int rt = 0; rt < 4; rt++)
      acc[g][rt] = mfma_bf16(a[rt], b[g], acc[g][rt]);
}
template <int N>
__device__ __forceinline__ void kloop(const u32x4*& ap, const u32x4*& wp,
                                      f32x4 acc[4][4]) {
  u32x4 a0[4], b0[4], a1[4], b1[4];
  ld4(a0, ap); ld4(b0, wp); ap += 256; wp += 256;
#pragma unroll 1
  for (int i = 0; i < (N - 1) / 2; i++) {
    ld4(a1, ap); ld4(b1, wp); ap += 256; wp += 256;
    mfma16(a0, b0, acc);
    ld4(a0, ap); ld4(b0, wp); ap += 256; wp += 256;
    mfma16(a1, b1, acc);
  }
  if constexpr ((N & 1) == 0) {
    ld4(a1, ap); ld4(b1, wp); ap += 256; wp += 256;
    mfma16(a0, b0, acc);
    mfma16(a1, b1, acc);
  } else {
    mfma16(a0, b0, acc);
  }
}

// ---------------- fused 2-layer LSTM + FC ----------------
// 256 blocks x 512 threads; block owns 64 batch rows for all 10 steps.
// LDS 158 KB (1 blk/CU, 2 waves/SIMD): x-tile + double-buffered h1/h2 in
// bf16 A-layout [kblk][row][8k] + biases; 3 barriers/step.
// K-loops rolled (see kloop); layer0 = 5-group x-part + 8-group h-part,
// layer1 = 8 + 8. c-state in AGPRs. Staging live set = 2 slots (64 regs).
__global__ __attribute__((amdgpu_flat_work_group_size(NTHREADS, NTHREADS),
                          amdgpu_waves_per_eu(2, 2)))
void lstm_fused(const float* __restrict__ x,
                const unsigned short* __restrict__ W0p,
                const unsigned short* __restrict__ W1p,
                const float* __restrict__ b0,
                const float* __restrict__ b1,
                const float* __restrict__ Wfc,
                const float* __restrict__ bfc,
                float* __restrict__ out) {
  __shared__ unsigned int lds_x[20 * 64 * 4];   // 20480 B
  __shared__ unsigned int lds_h1[16384];        // 65536 B = 2 bufs x [32 kblk][64 row][8k]
  __shared__ unsigned int lds_h2[16384];        // 65536 B
  __shared__ float lds_red[512];                // 2048 B
  __shared__ float lds_b0[1024];                // 4096 B
  __shared__ float lds_b1[1024];                // 4096 B   total 161792 B

  const int tid = threadIdx.x;
  const int wave = tid >> 6;
  const int lane = tid & 63;
  const int l15 = lane & 15;
  const int quad = lane >> 4;
  const long rowg0 = (long)blockIdx.x * 64;

  for (int i = tid; i < 16384; i += NTHREADS) { lds_h1[i] = 0u; lds_h2[i] = 0u; }
  for (int i = tid; i < 1024; i += NTHREADS) { lds_b0[i] = b0[i]; lds_b1[i] = b1[i]; }

  // persistent c-state pinned to AGPRs
  float c0a[2][4][4], c2a[2][4][4];
#pragma unroll
  for (int jt = 0; jt < 2; jt++)
#pragma unroll
    for (int rt = 0; rt < 4; rt++)
#pragma unroll
      for (int r = 0; r < 4; r++) {
        c0a[jt][rt][r] = agpr_st(0.f);
        c2a[jt][rt][r] = agpr_st(0.f);
      }
  float fc_acc = 0.0f;

  const u32x4* lxs = (const u32x4*)lds_x;
  const u32x4* lh1 = (const u32x4*)lds_h1;
  const u32x4* lh2 = (const u32x4*)lds_h2;
  unsigned short* lh1s = (unsigned short*)lds_h1;
  unsigned short* lh2s = (unsigned short*)lds_h2;
  const u32x4* w0q = (const u32x4*)W0p;
  const u32x4* w1q = (const u32x4*)W1p;

  for (int t = 0; t < 10; t++) {
    const int rd = t & 1;        // prev-h buffer
    const int wr = rd ^ 1;       // new-h buffer

    // ---- stage x_t -> lds_x (bf16 A-layout) ----
#pragma unroll
    for (int s = 0; s < 5; s++) {
      int p = tid + s * NTHREADS;          // 2560 f32x4 = 64 rows x 40 quads
      int row = p / 40;
      int kq = p - row * 40;
      const f32x4 v = __builtin_nontemporal_load(
          (const f32x4*)(x + (rowg0 + row) * 1600 + t * 160 + kq * 4));
      unsigned lo = (unsigned)f2bf(v[0]) | ((unsigned)f2bf(v[1]) << 16);
      unsigned hi = (unsigned)f2bf(v[2]) | ((unsigned)f2bf(v[3]) << 16);
      int base = (kq >> 1) * 256 + row * 4 + (kq & 1) * 2;
      lds_x[base] = lo;
      lds_x[base + 1] = hi;
    }
    __syncthreads();  // B1: x staged; h1[rd] stable from prev step

    // ======== layer 0: K=416 ([x_t | h1_prev]) ========
#pragma unroll 1
    for (int jt = 0; jt < 2; jt++) {
      const int nbb = wave * 2 + jt;
      f32x4 acc[4][4];
#pragma unroll
      for (int g = 0; g < 4; g++)
#pragma unroll
        for (int rt = 0; rt < 4; rt++) acc[g][rt] = (f32x4){0.f, 0.f, 0.f, 0.f};

      const u32x4* wp = w0q + (nbb * 52 + quad) * 64 + l15;
      const u32x4* ap = lxs + quad * 64 + l15;
      kloop<5>(ap, wp, acc);                       // x-part: k 0..159
      ap = lh1 + rd * 2048 + quad * 64 + l15;
      kloop<8>(ap, wp, acc);                       // h-part: k 160..415

      float b_i = lds_b0[0 * 256 + wave * 32 + jt * 16 + l15];
      float b_f = lds_b0[1 * 256 + wave * 32 + jt * 16 + l15];
      float b_g = lds_b0[2 * 256 + wave * 32 + jt * 16 + l15];
      float b_o = lds_b0[3 * 256 + wave * 32 + jt * 16 + l15];
#pragma unroll
      for (int rt = 0; rt < 4; rt++)
#pragma unroll
        for (int r = 0; r < 4; r++) {
          float iv = sigm(acc[0][rt][r] + b_i);
          float fv = sigm(acc[1][rt][r] + b_f);
          float gv = tanh_fast(acc[2][rt][r] + b_g);
          float ov = sigm(acc[3][rt][r] + b_o);
          float cn = fv * agpr_ld(c0a[jt][rt][r]) + iv * gv;
          c0a[jt][rt][r] = agpr_st(cn);
          int row = rt * 16 + quad * 4 + r;
          int col = wave * 32 + jt * 16 + l15;
          lh1s[wr * 16384 + ((col >> 3) * 64 + row) * 8 + (col & 7)] =
              f2bf(ov * tanh_fast(cn));
        }
    }
    __syncthreads();  // B2: h1[wr] complete

    // ======== layer 1: K=512 ([h1_new | h2_prev]) ========
#pragma unroll 1
    for (int jt = 0; jt < 2; jt++) {
      const int nbb = wave * 2 + jt;
      f32x4 acc[4][4];
#pragma unroll
      for (int g = 0; g < 4; g++)
#pragma unroll
        for (int rt = 0; rt < 4; rt++) acc[g][rt] = (f32x4){0.f, 0.f, 0.f, 0.f};

      const u32x4* wp = w1q + (nbb * 64 + quad) * 64 + l15;
      const u32x4* ap = lh1 + wr * 2048 + quad * 64 + l15;
      kloop<8>(ap, wp, acc);                       // h1_new part: k 0..255
      ap = lh2 + rd * 2048 + quad * 64 + l15;
      kloop<8>(ap, wp, acc);                       // h2_prev part: k 256..511

      float b_i = lds_b1[0 * 256 + wave * 32 + jt * 16 + l15];
      float b_f = lds_b1[1 * 256 + wave * 32 + jt * 16 + l15];
      float b_g = lds_b1[2 * 256 + wave * 32 + jt * 16 + l15];
      float b_o = lds_b1[3 * 256 + wave * 32 + jt * 16 + l15];
#pragma unroll
      for (int rt = 0; rt < 4; rt++)
#pragma unroll
        for (int r = 0; r < 4; r++) {
          float iv = sigm(acc[0][rt][r] + b_i);
          float fv = sigm(acc[1][rt][r] + b_f);
          float gv = tanh_fast(acc[2][rt][r] + b_g);
          float ov = sigm(acc[3][rt][r] + b_o);
          float cn = fv * agpr_ld(c2a[jt][rt][r]) + iv * gv;
          c2a[jt][rt][r] = agpr_st(cn);
          int row = rt * 16 + quad * 4 + r;
          int col = wave * 32 + jt * 16 + l15;
          lh2s[wr * 16384 + ((col >> 3) * 64 + row) * 8 + (col & 7)] =
              f2bf(ov * tanh_fast(cn));
        }
    }
    __syncthreads();  // B3: h2[wr] complete

    // ---- FC partial: logit += W_fc[t*256 + j] * h2_new[row][j] ----
    {
      int row = tid >> 3;
      int jq = (tid & 7) * 32;
      float s = 0.f;
#pragma unroll
      for (int kb = 0; kb < 4; kb++) {
        u32x4 hv = lh2[wr * 2048 + ((jq >> 3) + kb) * 64 + row];
        const f32x4 wA = *(const f32x4*)(Wfc + t * 256 + jq + kb * 8);
        const f32x4 wB = *(const f32x4*)(Wfc + t * 256 + jq + kb * 8 + 4);
#pragma unroll
        for (int e = 0; e < 2; e++) {
          unsigned u = hv[e];
          s += bf2f((unsigned short)(u & 0xffffu)) * wA[2 * e];
          s += bf2f((unsigned short)(u >> 16)) * wA[2 * e + 1];
        }
#pragma unroll
        for (int e = 0; e < 2; e++) {
          unsigned u = hv[2 + e];
          s += bf2f((unsigned short)(u & 0xffffu)) * wB[2 * e];
          s += bf2f((unsigned short)(u >> 16)) * wB[2 * e + 1];
        }
      }
      fc_acc += s;
    }
    // no barrier: next staging touches lds_x only; dbuf protects h regions.
  }

  lds_red[tid] = fc_acc;  // [row(64)][slot(8)]
  __syncthreads();
  if (tid < 64) {
    float s = 0.f;
#pragma unroll
    for (int e = 0; e < 8; e++) s += lds_red[tid * 8 + e];
    out[rowg0 + tid] = sigm(s + bfc[0]);
  }
}

extern "C" void kernel_launch(void* const* d_in, const int* in_sizes, int n_in,
                              void* d_out, int out_size, void* d_ws, size_t ws_size,
                              hipStream_t stream) {
  const float* x    = (const float*)d_in[0];
  const float* Wih0 = (const float*)d_in[1];
  const float* Whh0 = (const float*)d_in[2];
  const float* bih0 = (const float*)d_in[3];
  const float* bhh0 = (const float*)d_in[4];
  const float* Wih1 = (const float*)d_in[5];
  const float* Whh1 = (const float*)d_in[6];
  const float* bih1 = (const float*)d_in[7];
  const float* bhh1 = (const float*)d_in[8];
  const float* Wfc  = (const float*)d_in[9];
  const float* bfc  = (const float*)d_in[10];
  float* out = (float*)d_out;

  unsigned short* W0p = (unsigned short*)d_ws;         // 425984 bf16
  unsigned short* W1p = W0p + 16 * 52 * 4 * 128;       // 524288 bf16
  float* b0 = (float*)(W1p + 16 * 64 * 4 * 128);       // 1024 f32
  float* b1 = b0 + 1024;                               // 1024 f32

  const int total = 16 * 52 * 4 * 128 + 16 * 64 * 4 * 128 + 2048;
  pack_weights<<<(total + 255) / 256, 256, 0, stream>>>(
      Wih0, Whh0, bih0, bhh0, Wih1, Whh1, bih1, bhh1, W0p, W1p, b0, b1);
  lstm_fused<<<256, NTHREADS, 0, stream>>>(x, W0p, W1p, b0, b1, Wfc, bfc, out);
}